// Round 1
// baseline (15740.944 us; speedup 1.0000x reference)
//
#include <hip/hip_runtime.h>
#include <cmath>

#define Bc 32
#define Tc 32
#define Sc 64
#define Hc 512
#define Ec 512
#define Vc 32000
#define NEGC (-1e9f)

__device__ __forceinline__ float sigf(float x) { return 1.0f / (1.0f + expf(-x)); }

__device__ __forceinline__ float dot4(const float* a, const float* b) {
    float4 x = *(const float4*)a;
    float4 y = *(const float4*)b;
    return x.x * y.x + x.y * y.y + x.z * y.z + x.w * y.w;
}

// Initialize state: h = h0, c = c0, ah = 0
__global__ __launch_bounds__(256) void k_init(const float* __restrict__ h0,
                                              const float* __restrict__ c0,
                                              float* __restrict__ h, float* __restrict__ c,
                                              float* __restrict__ ah) {
    int i = blockIdx.x * 256 + threadIdx.x;
    if (i < Bc * Hc) { h[i] = h0[i]; c[i] = c0[i]; ah[i] = 0.0f; }
}

// proj[b][s][k] = sum_h W_a[k][h] * enc[s][b][h]
// grid: (Hc/256, Sc/8, Bc); enc tile of 8 s-rows staged in LDS
__global__ __launch_bounds__(256) void k_proj(const float* __restrict__ W_a,
                                              const float* __restrict__ enc,
                                              float* __restrict__ proj) {
    int k = blockIdx.x * 256 + threadIdx.x;
    int s0 = blockIdx.y * 8;
    int b = blockIdx.z;
    __shared__ float se[8][Hc];
    for (int i = threadIdx.x; i < 8 * Hc; i += 256) {
        int ss = i >> 9, hh = i & (Hc - 1);
        se[ss][hh] = enc[((size_t)(s0 + ss) * Bc + b) * Hc + hh];
    }
    __syncthreads();
    const float* wr = W_a + (size_t)k * Hc;
    float acc[8];
#pragma unroll
    for (int ss = 0; ss < 8; ++ss) acc[ss] = 0.0f;
    for (int h = 0; h < Hc; h += 4) {
        float4 w = *(const float4*)(wr + h);
#pragma unroll
        for (int ss = 0; ss < 8; ++ss) {
            acc[ss] = fmaf(w.x, se[ss][h + 0], acc[ss]);
            acc[ss] = fmaf(w.y, se[ss][h + 1], acc[ss]);
            acc[ss] = fmaf(w.z, se[ss][h + 2], acc[ss]);
            acc[ss] = fmaf(w.w, se[ss][h + 3], acc[ss]);
        }
    }
#pragma unroll
    for (int ss = 0; ss < 8; ++ss)
        proj[((size_t)b * Sc + s0 + ss) * Hc + k] = acc[ss];
}

// Fused gates GEMM + LSTM pointwise.
// block 256 = 32 b x 4 gates x 2 h; grid Hc/2 = 256 blocks.
// Each W_ih/W_hh row is read by exactly one block.
__global__ __launch_bounds__(256) void k_step1(const int* __restrict__ tgt,
                                               const float* __restrict__ emb,
                                               const float* __restrict__ W_ih,
                                               const float* __restrict__ W_hh,
                                               const float* __restrict__ b_ih,
                                               const float* __restrict__ b_hh,
                                               const float* __restrict__ h_prev,
                                               const float* __restrict__ c_prev,
                                               const float* __restrict__ ah_prev,
                                               float* __restrict__ h_new,
                                               float* __restrict__ c_new, int t) {
    int tid = threadIdx.x;
    int b = tid & 31;
    int q = (tid >> 5) & 3;
    int hl = tid >> 7;                 // 0..1
    int h = blockIdx.x * 2 + hl;
    int j = q * Hc + h;
    int w = tgt[b * Tc + t];
    const float* x = emb + (size_t)w * Ec;
    const float* wi = W_ih + (size_t)j * (Ec + Hc);
    const float* wh = W_hh + (size_t)j * Hc;
    const float* ap = ah_prev + b * Hc;
    const float* hp = h_prev + b * Hc;
    float acc = b_ih[j] + b_hh[j];
    for (int e = 0; e < Ec; e += 4) acc += dot4(x + e, wi + e);
    for (int k = 0; k < Hc; k += 4) acc += dot4(ap + k, wi + Ec + k);
    for (int k = 0; k < Hc; k += 4) acc += dot4(hp + k, wh + k);

    __shared__ float sg[2][4][32];
    sg[hl][q][b] = acc;
    __syncthreads();
    if (q == 0) {
        float iv = sigf(sg[hl][0][b]);
        float fv = sigf(sg[hl][1][b]);
        float gv = tanhf(sg[hl][2][b]);
        float ov = sigf(sg[hl][3][b]);
        int idx = b * Hc + h;
        float c2 = fv * c_prev[idx] + iv * gv;
        float h2 = ov * tanhf(c2);
        c_new[idx] = c2;
        h_new[idx] = h2;
    }
}

// Fused attention (scores -> masked softmax -> context) + ah2 projection.
// One block per batch element b.
__global__ __launch_bounds__(256) void k_attn(const float* __restrict__ enc,
                                              const float* __restrict__ proj,
                                              const float* __restrict__ h2,
                                              const float* __restrict__ W_c,
                                              const float* __restrict__ b_c,
                                              const int* __restrict__ len_src,
                                              float* __restrict__ ah_new) {
    int b = blockIdx.x;
    int tid = threadIdx.x;
    __shared__ float s_scores[Sc];
    __shared__ float s_hc[2 * Hc];     // [0,H)=h2  [H,2H)=ctx

    for (int k = tid; k < Hc; k += 256) s_hc[k] = h2[b * Hc + k];
    __syncthreads();

    // scores: 4 threads per s, each covers a contiguous 128-chunk of k
    {
        int s = tid >> 2, r = tid & 3;
        const float* pr = proj + ((size_t)b * Sc + s) * Hc + r * 128;
        const float* hh = s_hc + r * 128;
        float p = 0.0f;
        for (int k = 0; k < 128; k += 4) p += dot4(hh + k, pr + k);
        p += __shfl_xor(p, 1);
        p += __shfl_xor(p, 2);
        if (r == 0) s_scores[s] = p;
    }
    __syncthreads();

    // masked softmax over S=64 in the first wave
    if (tid < Sc) {
        int len = len_src[b];
        float sc = (tid < len) ? s_scores[tid] : NEGC;
        float mx = sc;
#pragma unroll
        for (int m = 32; m >= 1; m >>= 1) mx = fmaxf(mx, __shfl_xor(mx, m));
        float p = expf(sc - mx);
        float sum = p;
#pragma unroll
        for (int m = 32; m >= 1; m >>= 1) sum += __shfl_xor(sum, m);
        s_scores[tid] = p / sum;
    }
    __syncthreads();

    // ctx[h] = sum_s align[s] * enc[s][b][h]
    for (int h = tid; h < Hc; h += 256) {
        float acc = 0.0f;
        for (int s = 0; s < Sc; ++s)
            acc = fmaf(s_scores[s], enc[((size_t)s * Bc + b) * Hc + h], acc);
        s_hc[Hc + h] = acc;
    }
    __syncthreads();

    // ah2[k] = tanh([h2,ctx] . W_c[k] + b_c[k])
    for (int k = tid; k < Hc; k += 256) {
        const float* wc = W_c + (size_t)k * (2 * Hc);
        float acc = b_c[k];
        for (int j = 0; j < 2 * Hc; j += 4) {
            float4 w = *(const float4*)(wc + j);
            acc = fmaf(w.x, s_hc[j + 0], acc);
            acc = fmaf(w.y, s_hc[j + 1], acc);
            acc = fmaf(w.z, s_hc[j + 2], acc);
            acc = fmaf(w.w, s_hc[j + 3], acc);
        }
        ah_new[b * Hc + k] = tanhf(acc);
    }
}

// logits[b][v] = ah2[b] . W_o[v] + b_o[v]
// block 256 = 32 b x 8 v (b = tid>>3), so each W_o row is read by one block.
__global__ __launch_bounds__(256) void k_logits(const float* __restrict__ ah2,
                                                const float* __restrict__ W_o,
                                                const float* __restrict__ b_o,
                                                float* __restrict__ out) {
    int tid = threadIdx.x;
    int vl = tid & 7;
    int b = tid >> 3;
    int v = blockIdx.x * 8 + vl;
    const float* wr = W_o + (size_t)v * Hc;
    const float* ar = ah2 + b * Hc;
    float acc = b_o[v];
    for (int h = 0; h < Hc; h += 4) acc += dot4(wr + h, ar + h);
    out[(size_t)b * Vc + v] = acc;
}

// per-b: max+argmax (first-occurrence tiebreak) and logsumexp over V
__global__ __launch_bounds__(256) void k_reduce(const float* __restrict__ logits,
                                                float* __restrict__ lse,
                                                float* __restrict__ words) {
    int b = blockIdx.x, tid = threadIdx.x;
    const float* row = logits + (size_t)b * Vc;
    float mx = -INFINITY;
    int mi = 0;
    for (int v = tid; v < Vc; v += 256) {
        float x = row[v];
        if (x > mx) { mx = x; mi = v; }
    }
    __shared__ float smx[256];
    __shared__ int smi[256];
    __shared__ float ssum[256];
    smx[tid] = mx; smi[tid] = mi;
    __syncthreads();
    for (int off = 128; off; off >>= 1) {
        if (tid < off) {
            float o = smx[tid + off]; int oi = smi[tid + off];
            if (o > smx[tid] || (o == smx[tid] && oi < smi[tid])) { smx[tid] = o; smi[tid] = oi; }
        }
        __syncthreads();
    }
    float gmx = smx[0];
    float s = 0.0f;
    for (int v = tid; v < Vc; v += 256) s += expf(row[v] - gmx);
    ssum[tid] = s;
    __syncthreads();
    for (int off = 128; off; off >>= 1) {
        if (tid < off) ssum[tid] += ssum[tid + off];
        __syncthreads();
    }
    if (tid == 0) {
        lse[b] = gmx + logf(ssum[0]);
        words[b] = (float)smi[0];
    }
}

// logp = logits - lse[b], in place
__global__ __launch_bounds__(256) void k_norm(float* __restrict__ out,
                                              const float* __restrict__ lse) {
    int b = blockIdx.y;
    int v = blockIdx.x * 256 + threadIdx.x;
    out[(size_t)b * Vc + v] -= lse[b];
}

extern "C" void kernel_launch(void* const* d_in, const int* in_sizes, int n_in,
                              void* d_out, int out_size, void* d_ws, size_t ws_size,
                              hipStream_t stream) {
    const int*   tgt     = (const int*)d_in[0];
    const int*   len_src = (const int*)d_in[1];
    const float* enc     = (const float*)d_in[2];
    const float* h0      = (const float*)d_in[3];
    const float* c0      = (const float*)d_in[4];
    const float* emb     = (const float*)d_in[5];
    const float* W_ih    = (const float*)d_in[6];
    const float* W_hh    = (const float*)d_in[7];
    const float* b_ih    = (const float*)d_in[8];
    const float* b_hh    = (const float*)d_in[9];
    const float* W_a     = (const float*)d_in[10];
    const float* W_c     = (const float*)d_in[11];
    const float* b_c     = (const float*)d_in[12];
    const float* W_o     = (const float*)d_in[13];
    const float* b_o     = (const float*)d_in[14];

    float* out = (float*)d_out;
    float* ws = (float*)d_ws;

    float* proj = ws;                          // B*S*H = 1048576
    float* hbuf = ws + 1048576;                // 2 * 16384
    float* cbuf = hbuf + 2 * Bc * Hc;
    float* abuf = cbuf + 2 * Bc * Hc;
    float* lse  = abuf + 2 * Bc * Hc;          // 32
    float* out_words = out + (size_t)(Tc - 1) * Bc * Vc;

    k_init<<<64, 256, 0, stream>>>(h0, c0, hbuf, cbuf, abuf);
    {
        dim3 g(Hc / 256, Sc / 8, Bc);
        k_proj<<<g, 256, 0, stream>>>(W_a, enc, proj);
    }

    int cur = 0;
    for (int t = 0; t < Tc - 1; ++t) {
        int nxt = 1 - cur;
        float* hP = hbuf + cur * Bc * Hc; float* hN = hbuf + nxt * Bc * Hc;
        float* cP = cbuf + cur * Bc * Hc; float* cN = cbuf + nxt * Bc * Hc;
        float* aP = abuf + cur * Bc * Hc; float* aN = abuf + nxt * Bc * Hc;

        k_step1<<<Hc / 2, 256, 0, stream>>>(tgt, emb, W_ih, W_hh, b_ih, b_hh,
                                            hP, cP, aP, hN, cN, t);
        k_attn<<<Bc, 256, 0, stream>>>(enc, proj, hN, W_c, b_c, len_src, aN);

        float* lt = out + (size_t)t * Bc * Vc;
        k_logits<<<Vc / 8, 256, 0, stream>>>(aN, W_o, b_o, lt);
        k_reduce<<<Bc, 256, 0, stream>>>(lt, lse, out_words + t * Bc);
        dim3 gn(Vc / 256, Bc);
        k_norm<<<gn, 256, 0, stream>>>(lt, lse);
        cur = nxt;
    }
}

// Round 2
// 4108.849 us; speedup vs baseline: 3.8310x; 3.8310x over previous
//
#include <hip/hip_runtime.h>
#include <cmath>

#define Bc 32
#define Tc 32
#define Sc 64
#define Hc 512
#define Ec 512
#define Vc 32000
#define NEGC (-1e9f)
#define BH (Bc * Hc)
#define Mtot ((Tc - 1) * Bc)   // 992

__device__ __forceinline__ float sigf(float x) { return 1.0f / (1.0f + expf(-x)); }

__device__ __forceinline__ float dot4(const float* a, const float* b) {
    float4 x = *(const float4*)a;
    float4 y = *(const float4*)b;
    return x.x * y.x + x.y * y.y + x.z * y.z + x.w * y.w;
}

// Initialize state: h = h0, c = c0, ah_slot0 = 0
__global__ __launch_bounds__(256) void k_init(const float* __restrict__ h0,
                                              const float* __restrict__ c0,
                                              float* __restrict__ h, float* __restrict__ c,
                                              float* __restrict__ ah0) {
    int i = blockIdx.x * 256 + threadIdx.x;
    if (i < BH) { h[i] = h0[i]; c[i] = c0[i]; ah0[i] = 0.0f; }
}

// proj[b][s][k] = sum_h W_a[k][h] * enc[s][b][h]
__global__ __launch_bounds__(256) void k_proj(const float* __restrict__ W_a,
                                              const float* __restrict__ enc,
                                              float* __restrict__ proj) {
    int k = blockIdx.x * 256 + threadIdx.x;
    int s0 = blockIdx.y * 8;
    int b = blockIdx.z;
    __shared__ float se[8][Hc];
    for (int i = threadIdx.x; i < 8 * Hc; i += 256) {
        int ss = i >> 9, hh = i & (Hc - 1);
        se[ss][hh] = enc[((size_t)(s0 + ss) * Bc + b) * Hc + hh];
    }
    __syncthreads();
    const float* wr = W_a + (size_t)k * Hc;
    float acc[8];
#pragma unroll
    for (int ss = 0; ss < 8; ++ss) acc[ss] = 0.0f;
    for (int h = 0; h < Hc; h += 4) {
        float4 w = *(const float4*)(wr + h);
#pragma unroll
        for (int ss = 0; ss < 8; ++ss) {
            acc[ss] = fmaf(w.x, se[ss][h + 0], acc[ss]);
            acc[ss] = fmaf(w.y, se[ss][h + 1], acc[ss]);
            acc[ss] = fmaf(w.z, se[ss][h + 2], acc[ss]);
            acc[ss] = fmaf(w.w, se[ss][h + 3], acc[ss]);
        }
    }
#pragma unroll
    for (int ss = 0; ss < 8; ++ss)
        proj[((size_t)b * Sc + s0 + ss) * Hc + k] = acc[ss];
}

// Fused gates GEMM + LSTM pointwise. 4 independent accumulators per dot.
__global__ __launch_bounds__(256) void k_step1(const int* __restrict__ tgt,
                                               const float* __restrict__ emb,
                                               const float* __restrict__ W_ih,
                                               const float* __restrict__ W_hh,
                                               const float* __restrict__ b_ih,
                                               const float* __restrict__ b_hh,
                                               const float* __restrict__ h_prev,
                                               const float* __restrict__ c_prev,
                                               const float* __restrict__ ah_prev,
                                               float* __restrict__ h_new,
                                               float* __restrict__ c_new, int t) {
    int tid = threadIdx.x;
    int b = tid & 31;
    int q = (tid >> 5) & 3;
    int hl = tid >> 7;
    int h = blockIdx.x * 2 + hl;
    int j = q * Hc + h;
    int w = tgt[b * Tc + t];
    const float* x = emb + (size_t)w * Ec;
    const float* wi = W_ih + (size_t)j * (Ec + Hc);
    const float* wh = W_hh + (size_t)j * Hc;
    const float* ap = ah_prev + b * Hc;
    const float* hp = h_prev + b * Hc;
    float a0 = 0.f, a1 = 0.f, a2 = 0.f, a3 = 0.f;
    for (int e = 0; e < Ec; e += 16) {
        a0 += dot4(x + e, wi + e);
        a1 += dot4(x + e + 4, wi + e + 4);
        a2 += dot4(x + e + 8, wi + e + 8);
        a3 += dot4(x + e + 12, wi + e + 12);
    }
    for (int k = 0; k < Hc; k += 16) {
        a0 += dot4(ap + k, wi + Ec + k);
        a1 += dot4(ap + k + 4, wi + Ec + k + 4);
        a2 += dot4(ap + k + 8, wi + Ec + k + 8);
        a3 += dot4(ap + k + 12, wi + Ec + k + 12);
    }
    for (int k = 0; k < Hc; k += 16) {
        a0 += dot4(hp + k, wh + k);
        a1 += dot4(hp + k + 4, wh + k + 4);
        a2 += dot4(hp + k + 8, wh + k + 8);
        a3 += dot4(hp + k + 12, wh + k + 12);
    }
    float acc = b_ih[j] + b_hh[j] + ((a0 + a1) + (a2 + a3));

    __shared__ float sg[2][4][32];
    sg[hl][q][b] = acc;
    __syncthreads();
    if (q == 0) {
        float iv = sigf(sg[hl][0][b]);
        float fv = sigf(sg[hl][1][b]);
        float gv = tanhf(sg[hl][2][b]);
        float ov = sigf(sg[hl][3][b]);
        int idx = b * Hc + h;
        float c2 = fv * c_prev[idx] + iv * gv;
        float h2 = ov * tanhf(c2);
        c_new[idx] = c2;
        h_new[idx] = h2;
    }
}

// scores + masked softmax -> align[b][s]
__global__ __launch_bounds__(256) void k_score(const float* __restrict__ proj,
                                               const float* __restrict__ h2,
                                               const int* __restrict__ len_src,
                                               float* __restrict__ align) {
    int b = blockIdx.x;
    int tid = threadIdx.x;
    __shared__ float sh[Hc];
    __shared__ float ss[Sc];
    for (int k = tid; k < Hc; k += 256) sh[k] = h2[b * Hc + k];
    __syncthreads();
    {
        int s = tid >> 2, r = tid & 3;
        const float* pr = proj + ((size_t)b * Sc + s) * Hc + r * 128;
        const float* hh = sh + r * 128;
        float p0 = 0.f, p1 = 0.f;
        for (int k = 0; k < 128; k += 8) {
            p0 += dot4(hh + k, pr + k);
            p1 += dot4(hh + k + 4, pr + k + 4);
        }
        float p = p0 + p1;
        p += __shfl_xor(p, 1);
        p += __shfl_xor(p, 2);
        if (r == 0) ss[s] = p;
    }
    __syncthreads();
    if (tid < Sc) {
        int len = len_src[b];
        float sc = (tid < len) ? ss[tid] : NEGC;
        float mx = sc;
#pragma unroll
        for (int m = 32; m >= 1; m >>= 1) mx = fmaxf(mx, __shfl_xor(mx, m));
        float p = expf(sc - mx);
        float sum = p;
#pragma unroll
        for (int m = 32; m >= 1; m >>= 1) sum += __shfl_xor(sum, m);
        align[b * Sc + tid] = p / sum;
    }
}

// ctx[b][h] = sum_s align[b][s] * enc[s][b][h]; grid (4 h-slices, 32 b)
__global__ __launch_bounds__(256) void k_ctx(const float* __restrict__ enc,
                                             const float* __restrict__ align,
                                             float* __restrict__ ctx) {
    int hs = blockIdx.x, b = blockIdx.y;
    int tid = threadIdx.x;
    __shared__ float sal[Sc];
    __shared__ float part[2][128];
    if (tid < Sc) sal[tid] = align[b * Sc + tid];
    __syncthreads();
    int half = tid >> 7;
    int hl = tid & 127;
    int h = hs * 128 + hl;
    float acc = 0.0f;
    for (int s = half * 32; s < half * 32 + 32; ++s)
        acc = fmaf(sal[s], enc[((size_t)s * Bc + b) * Hc + h], acc);
    part[half][hl] = acc;
    __syncthreads();
    if (half == 0) ctx[b * Hc + h] = part[0][hl] + part[1][hl];
}

// ah2[b][k] = tanh(W_c[k] . [h2;ctx] + b_c[k]); grid 64 blocks (8 k x 32 b)
__global__ __launch_bounds__(256) void k_wc(const float* __restrict__ h2,
                                            const float* __restrict__ ctx,
                                            const float* __restrict__ W_c,
                                            const float* __restrict__ b_c,
                                            float* __restrict__ ah_new) {
    int tid = threadIdx.x;
    int kl = tid >> 5;
    int b = tid & 31;
    int k = blockIdx.x * 8 + kl;
    const float* wc = W_c + (size_t)k * (2 * Hc);
    const float* hp = h2 + b * Hc;
    const float* cp = ctx + b * Hc;
    float a0 = 0.f, a1 = 0.f, a2 = 0.f, a3 = 0.f;
    for (int j = 0; j < Hc; j += 16) {
        a0 += dot4(hp + j, wc + j);
        a1 += dot4(hp + j + 4, wc + j + 4);
        a2 += dot4(hp + j + 8, wc + j + 8);
        a3 += dot4(hp + j + 12, wc + j + 12);
    }
    const float* wc2 = wc + Hc;
    for (int j = 0; j < Hc; j += 16) {
        a0 += dot4(cp + j, wc2 + j);
        a1 += dot4(cp + j + 4, wc2 + j + 4);
        a2 += dot4(cp + j + 8, wc2 + j + 8);
        a3 += dot4(cp + j + 12, wc2 + j + 12);
    }
    ah_new[b * Hc + k] = tanhf(b_c[k] + ((a0 + a1) + (a2 + a3)));
}

// Batched logits GEMM: C[m][n] = A[m][:] . W_o[n][:] + b_o[n]
// A = all ah2, M=992, K=512, N=32000. Tile 128m x 128n, Kc=32.
// Per thread: 8m x 8n accumulators; m,n split as {g*64 + t*4 + i}.
__global__ __launch_bounds__(256) void k_biglogits(const float* __restrict__ A,
                                                   const float* __restrict__ W_o,
                                                   const float* __restrict__ b_o,
                                                   float* __restrict__ out) {
    __shared__ float At[32][128];
    __shared__ float Bt[32][128];
    int tid = threadIdx.x;
    int n_base = blockIdx.x * 128;
    int m_base = blockIdx.y * 128;
    int tn = tid & 15, tm = tid >> 4;

    float acc[2][4][2][4];   // [mg][mi][ng][ni]
#pragma unroll
    for (int mg = 0; mg < 2; ++mg)
#pragma unroll
        for (int mi = 0; mi < 4; ++mi)
#pragma unroll
            for (int ng = 0; ng < 2; ++ng)
#pragma unroll
                for (int ni = 0; ni < 4; ++ni) acc[mg][mi][ng][ni] = 0.0f;

    int srow = tid >> 1;
    int koff = (tid & 1) * 16;
    int gm = m_base + srow;
    const float* arow = A + (size_t)gm * Hc + koff;
    const float* brow = W_o + (size_t)(n_base + srow) * Hc + koff;

    for (int kc = 0; kc < Hc; kc += 32) {
        float av[16], bv[16];
#pragma unroll
        for (int i = 0; i < 4; ++i) {
            float4 t4 = (gm < Mtot) ? *(const float4*)(arow + kc + i * 4)
                                    : make_float4(0.f, 0.f, 0.f, 0.f);
            av[i * 4 + 0] = t4.x; av[i * 4 + 1] = t4.y; av[i * 4 + 2] = t4.z; av[i * 4 + 3] = t4.w;
            float4 u4 = *(const float4*)(brow + kc + i * 4);
            bv[i * 4 + 0] = u4.x; bv[i * 4 + 1] = u4.y; bv[i * 4 + 2] = u4.z; bv[i * 4 + 3] = u4.w;
        }
        __syncthreads();
#pragma unroll
        for (int i = 0; i < 16; ++i) {
            At[koff + i][srow] = av[i];
            Bt[koff + i][srow] = bv[i];
        }
        __syncthreads();
#pragma unroll
        for (int k = 0; k < 32; ++k) {
            float4 a0 = *(const float4*)&At[k][tm * 4];
            float4 a1 = *(const float4*)&At[k][64 + tm * 4];
            float4 b0 = *(const float4*)&Bt[k][tn * 4];
            float4 b1 = *(const float4*)&Bt[k][64 + tn * 4];
            float am[2][4] = {{a0.x, a0.y, a0.z, a0.w}, {a1.x, a1.y, a1.z, a1.w}};
            float bn[2][4] = {{b0.x, b0.y, b0.z, b0.w}, {b1.x, b1.y, b1.z, b1.w}};
#pragma unroll
            for (int mg = 0; mg < 2; ++mg)
#pragma unroll
                for (int mi = 0; mi < 4; ++mi)
#pragma unroll
                    for (int ng = 0; ng < 2; ++ng)
#pragma unroll
                        for (int ni = 0; ni < 4; ++ni)
                            acc[mg][mi][ng][ni] = fmaf(am[mg][mi], bn[ng][ni], acc[mg][mi][ng][ni]);
        }
        __syncthreads();
    }

#pragma unroll
    for (int ng = 0; ng < 2; ++ng) {
        int n = n_base + ng * 64 + tn * 4;
        float4 bo = *(const float4*)(b_o + n);
#pragma unroll
        for (int mg = 0; mg < 2; ++mg)
#pragma unroll
            for (int mi = 0; mi < 4; ++mi) {
                int m = m_base + mg * 64 + tm * 4 + mi;
                if (m < Mtot) {
                    float4 v;
                    v.x = acc[mg][mi][ng][0] + bo.x;
                    v.y = acc[mg][mi][ng][1] + bo.y;
                    v.z = acc[mg][mi][ng][2] + bo.z;
                    v.w = acc[mg][mi][ng][3] + bo.w;
                    *(float4*)(out + (size_t)m * Vc + n) = v;
                }
            }
    }
}

// Per row m: argmax (first tiebreak) + logsumexp, then subtract in place; words out.
__global__ __launch_bounds__(256) void k_reduce_norm(float* __restrict__ out,
                                                     float* __restrict__ words) {
    int m = blockIdx.x, tid = threadIdx.x;
    float* row = out + (size_t)m * Vc;
    float mx = -INFINITY;
    int mi = 0;
    for (int v = tid; v < Vc; v += 256) {
        float x = row[v];
        if (x > mx) { mx = x; mi = v; }
    }
    __shared__ float smx[256];
    __shared__ int smi[256];
    __shared__ float ssum[256];
    smx[tid] = mx; smi[tid] = mi;
    __syncthreads();
    for (int off = 128; off; off >>= 1) {
        if (tid < off) {
            float o = smx[tid + off]; int oi = smi[tid + off];
            if (o > smx[tid] || (o == smx[tid] && oi < smi[tid])) { smx[tid] = o; smi[tid] = oi; }
        }
        __syncthreads();
    }
    float gmx = smx[0];
    float s = 0.0f;
    for (int v = tid; v < Vc; v += 256) s += expf(row[v] - gmx);
    ssum[tid] = s;
    __syncthreads();
    for (int off = 128; off; off >>= 1) {
        if (tid < off) ssum[tid] += ssum[tid + off];
        __syncthreads();
    }
    float lse = gmx + logf(ssum[0]);
    __syncthreads();
    for (int v = tid; v < Vc; v += 256) row[v] -= lse;
    if (tid == 0) words[m] = (float)smi[0];
}

extern "C" void kernel_launch(void* const* d_in, const int* in_sizes, int n_in,
                              void* d_out, int out_size, void* d_ws, size_t ws_size,
                              hipStream_t stream) {
    const int*   tgt     = (const int*)d_in[0];
    const int*   len_src = (const int*)d_in[1];
    const float* enc     = (const float*)d_in[2];
    const float* h0      = (const float*)d_in[3];
    const float* c0      = (const float*)d_in[4];
    const float* emb     = (const float*)d_in[5];
    const float* W_ih    = (const float*)d_in[6];
    const float* W_hh    = (const float*)d_in[7];
    const float* b_ih    = (const float*)d_in[8];
    const float* b_hh    = (const float*)d_in[9];
    const float* W_a     = (const float*)d_in[10];
    const float* W_c     = (const float*)d_in[11];
    const float* b_c     = (const float*)d_in[12];
    const float* W_o     = (const float*)d_in[13];
    const float* b_o     = (const float*)d_in[14];

    float* out = (float*)d_out;
    float* ws = (float*)d_ws;

    float* proj   = ws;                          // B*S*H = 1,048,576
    float* hbuf   = proj + (size_t)Bc * Sc * Hc; // 2 * BH
    float* cbuf   = hbuf + 2 * BH;               // 2 * BH
    float* ah_all = cbuf + 2 * BH;               // 32 * BH (slot0 = zeros)
    float* ctx    = ah_all + 32 * BH;            // BH
    float* align  = ctx + BH;                    // 32*64
    float* out_words = out + (size_t)(Tc - 1) * Bc * Vc;

    k_init<<<64, 256, 0, stream>>>(h0, c0, hbuf, cbuf, ah_all);
    {
        dim3 g(Hc / 256, Sc / 8, Bc);
        k_proj<<<g, 256, 0, stream>>>(W_a, enc, proj);
    }

    int cur = 0;
    for (int t = 0; t < Tc - 1; ++t) {
        int nxt = 1 - cur;
        float* hP = hbuf + cur * BH; float* hN = hbuf + nxt * BH;
        float* cP = cbuf + cur * BH; float* cN = cbuf + nxt * BH;
        float* aP = ah_all + (size_t)t * BH;
        float* aN = ah_all + (size_t)(t + 1) * BH;

        k_step1<<<Hc / 2, 256, 0, stream>>>(tgt, emb, W_ih, W_hh, b_ih, b_hh,
                                            hP, cP, aP, hN, cN, t);
        k_score<<<Bc, 256, 0, stream>>>(proj, hN, len_src, align);
        {
            dim3 g(4, Bc);
            k_ctx<<<g, 256, 0, stream>>>(enc, align, ctx);
        }
        k_wc<<<64, 256, 0, stream>>>(hN, ctx, W_c, b_c, aN);
        cur = nxt;
    }

    {
        dim3 g(Vc / 128, (Mtot + 127) / 128);    // 250 x 8
        k_biglogits<<<g, 256, 0, stream>>>(ah_all + BH, W_o, b_o, out);
    }
    k_reduce_norm<<<Mtot, 256, 0, stream>>>(out, out_words);
}